// Round 10
// baseline (199.435 us; speedup 1.0000x reference)
//
#include <hip/hip_runtime.h>

// H=16, DK=DV=64, D=1024, N=M=2048.
// scores[h,n,m] = ((A_h^T q_n + vh_h) . k_m)/8 + row-consts (drop in softmax),
//   A_h[i][j] = sum_d Wq[h,i,d]*Wk[h,j,d],  vh_h[j] = sum_d Wk[h,j,d]*bq[h,d].
// r_h[v] = sum_m g_h[m]*values[m,v],  g_h[m] = sum_n exp(s[n,m])/l[n],
// l[n] = sum_m exp(s[n,m]);  pooled = r.Wv + 2048*sum_h bv;  out = pooled.Wo^T+bo.
// No max-tracking: |s|max ~ 27 << 88 -> exp2 safe in fp32.
//
// v10 = v9 two-pass + occupancy & launch-count fixes:
//  - pass1 splits KEYS 2-way (partial l via atomicAdd), pass2 splits N 2-way
//    (partial g -> partial r fold; u=1/l inline): both grids (64,16)=1024
//    = 4 blocks/CU = 4 waves/SIMD (v9 was grid-capped at 2 waves/SIMD).
//  - prep computes A per-head with REGISTER accumulation over the 8 k-chunks
//    (acc[4] floatx4) and writes Atlg/vhg directly: reduceA kernel + 2MB
//    Apart round-trip deleted. 5 kernels total.
//  - v8's SWZ LDS swizzle kept everywhere (conflicts 4.8M->98K proven).

typedef __attribute__((ext_vector_type(4))) float floatx4;
typedef __attribute__((ext_vector_type(8))) short shortx8;

__device__ inline unsigned short f2bf(float f) {
    unsigned int u = __float_as_uint(f);
    u += 0x7FFFu + ((u >> 16) & 1u);   // RNE
    return (unsigned short)(u >> 16);
}
__device__ inline float bf2f(unsigned short s) {
    return __uint_as_float(((unsigned int)s) << 16);
}

// byte offset into a [R][64]-bf16 LDS tile, bank-conflict-free (v8-proven):
#define SWZ(row, bc) ((row) * 128 + ((bc) ^ (((row) & 7) << 4)))
#define QSCALE 0.18033688f   /* 0.125 * log2(e) */

// =================== prep: per-head A (reg-accumulated) / K-cvt / zeros =====
// grid 32: blocks 0-15: head h -> Atlg (A^T bf16) + vhg, 8 k-chunks in regs
//          blocks 16-31: K bf16 convert + zero l_ws, r_ws
__global__ __launch_bounds__(256) void prep_kernel(
    const float* __restrict__ Wq, const float* __restrict__ Wk,
    const float* __restrict__ bq, const float* __restrict__ keys,
    unsigned short* __restrict__ Atlg, float* __restrict__ vhg,
    unsigned short* __restrict__ Kb, float* __restrict__ l_ws,
    float* __restrict__ r_ws) {
    const int tid = threadIdx.x;
    const int bx = blockIdx.x;
    __shared__ __align__(16) unsigned char sm[36352];
    if (bx < 16) {
        const int h = bx;
        unsigned short* wq = (unsigned short*)sm;            // 64*136 ushort
        unsigned short* wk = (unsigned short*)(sm + 17408);  // 64*136 ushort
        float* bqs = (float*)(sm + 34816);                   // 128
        float* vred = (float*)(sm + 35328);                  // 4*64
        const int w = tid >> 6, lane = tid & 63;
        const int ln = lane & 15, quad = lane >> 4;
        floatx4 acc[4] = {};
        float vreg = 0.f;
        for (int g = 0; g < 8; ++g) {
            const int c0 = g * 128;
            {
                int row = tid >> 2, cs = (tid & 3) * 32;
                const float* wqp = Wq + (size_t)(h * 64 + row) * 1024 + c0 + cs;
                const float* wkp = Wk + (size_t)(h * 64 + row) * 1024 + c0 + cs;
                #pragma unroll
                for (int u = 0; u < 8; ++u) {
                    float4 a = *(const float4*)&wqp[u * 4];
                    float4 b = *(const float4*)&wkp[u * 4];
                    *(ushort4*)&wq[row * 136 + cs + u * 4] =
                        (ushort4){f2bf(a.x), f2bf(a.y), f2bf(a.z), f2bf(a.w)};
                    *(ushort4*)&wk[row * 136 + cs + u * 4] =
                        (ushort4){f2bf(b.x), f2bf(b.y), f2bf(b.z), f2bf(b.w)};
                }
                if (tid < 128) bqs[tid] = bq[h * 1024 + c0 + tid];
            }
            __syncthreads();
            {   // vh chunk accumulate (j = tid&63, d-quarter = tid>>6)
                const int j = tid & 63, half = tid >> 6;
                #pragma unroll
                for (int u = 0; u < 32; ++u)
                    vreg += bf2f(wk[j * 136 + half * 32 + u]) * bqs[half * 32 + u];
            }
            shortx8 af[4];
            #pragma unroll
            for (int kk = 0; kk < 4; ++kk)
                af[kk] = *(shortx8*)&wq[(w * 16 + ln) * 136 + kk * 32 + quad * 8];
            #pragma unroll
            for (int cn = 0; cn < 4; ++cn)
                #pragma unroll
                for (int kk = 0; kk < 4; ++kk) {
                    shortx8 bf_ = *(shortx8*)&wk[(cn * 16 + ln) * 136 + kk * 32 + quad * 8];
                    acc[cn] = __builtin_amdgcn_mfma_f32_16x16x32_bf16(af[kk], bf_, acc[cn], 0, 0, 0);
                }
            __syncthreads();   // LDS free for next chunk (or final transpose)
        }
        // A^T via LDS transpose (wq region dead), vh final reduce
        vred[(tid >> 6) * 64 + (tid & 63)] = vreg;
        unsigned short* atl = (unsigned short*)sm;   // [64][72] shorts
        #pragma unroll
        for (int cn = 0; cn < 4; ++cn)
            #pragma unroll
            for (int r = 0; r < 4; ++r)
                atl[(cn * 16 + ln) * 72 + w * 16 + quad * 4 + r] = f2bf(acc[cn][r]);
        __syncthreads();
        #pragma unroll
        for (int k = 0; k < 2; ++k) {
            int seg = tid * 2 + k, row = seg >> 3, off = (seg & 7) * 8;
            *(shortx8*)&Atlg[h * 4096 + row * 64 + off] =
                *(shortx8*)&atl[row * 72 + off];
        }
        if (tid < 64)
            vhg[h * 64 + tid] = vred[tid] + vred[64 + tid] +
                                vred[128 + tid] + vred[192 + tid];
    } else {
        int bk = bx - 16;
        int base = (bk * 256 + tid) * 32;
        #pragma unroll
        for (int u = 0; u < 8; ++u) {
            float4 a = *(const float4*)&keys[base + u * 4];
            *(ushort4*)&Kb[base + u * 4] =
                (ushort4){f2bf(a.x), f2bf(a.y), f2bf(a.z), f2bf(a.w)};
        }
        #pragma unroll
        for (int i = 0; i < 8; ++i) l_ws[bk * 2048 + tid * 8 + i] = 0.f;
        if (tid < 64) r_ws[bk * 64 + tid] = 0.f;
    }
}

// =================== pass1: l[h,n] += sum_{m in half} exp2(qhat.k) ==========
// grid (64,16): blockIdx.x = ntile*2 + khalf. 64 q-rows, 1024 keys (16 steps
// of 64). 4 waves; wave w -> rows w*16..+15. K-tile dbuf+SWZ. khalf==0 block
// also writes Qhs (identical in both halves). Partial l via atomicAdd.
__global__ __launch_bounds__(256, 4) void pass1_kernel(
    const float* __restrict__ queries, const unsigned short* __restrict__ Atlg,
    const float* __restrict__ vhg, const unsigned short* __restrict__ Kb,
    unsigned short* __restrict__ Qhs, float* __restrict__ l_ws) {
    const int h = blockIdx.y;
    const int nt = blockIdx.x >> 1, kh = blockIdx.x & 1;
    const int n0 = nt * 64;
    const int tid = threadIdx.x;
    const int w = tid >> 6, lane = tid & 63;
    const int ln = lane & 15, quad = lane >> 4;

    __shared__ __align__(16) unsigned char lds[27648];
    __shared__ float vhs[64];
    // phase A: qstage @0 (9216), Atl @9216 (9216)
    // loop:    Kbuf[2] @0..16384 (SWZ [64][64]), qh @18432 ([64][72])
    unsigned short* qstage = (unsigned short*)lds;
    unsigned short* Atl = (unsigned short*)(lds + 9216);
    unsigned short* qh = (unsigned short*)(lds + 18432);

    // ---- phase A: stage queries (bf16), Atl (coalesced), vhs ---------------
    {
        int row = tid >> 2, c16 = (tid & 3) * 16;
        const float* qp = queries + (size_t)(n0 + row) * 64 + c16;
        #pragma unroll
        for (int u = 0; u < 4; ++u) {
            float4 a = *(const float4*)&qp[u * 4];
            *(ushort4*)&qstage[row * 72 + c16 + u * 4] =
                (ushort4){f2bf(a.x), f2bf(a.y), f2bf(a.z), f2bf(a.w)};
        }
        #pragma unroll
        for (int u = 0; u < 2; ++u)
            *(shortx8*)&Atl[row * 72 + c16 + u * 8] =
                *(const shortx8*)&Atlg[h * 4096 + row * 64 + c16 + u * 8];
    }
    if (tid < 64) vhs[tid] = vhg[h * 64 + tid];
    __syncthreads();

    // ---- phase B: qhat via MFMA; wave w -> rowtile w -----------------------
    {
        shortx8 qa[2];
        #pragma unroll
        for (int kk = 0; kk < 2; ++kk)
            qa[kk] = *(shortx8*)&qstage[(w * 16 + ln) * 72 + kk * 32 + quad * 8];
        #pragma unroll
        for (int cn = 0; cn < 4; ++cn) {
            floatx4 acc = {};
            #pragma unroll
            for (int kk = 0; kk < 2; ++kk) {
                shortx8 bfr = *(shortx8*)&Atl[(cn * 16 + ln) * 72 + kk * 32 + quad * 8];
                acc = __builtin_amdgcn_mfma_f32_16x16x32_bf16(qa[kk], bfr, acc, 0, 0, 0);
            }
            #pragma unroll
            for (int r = 0; r < 4; ++r)
                qh[(w * 16 + quad * 4 + r) * 72 + cn * 16 + ln] =
                    f2bf((acc[r] + vhs[cn * 16 + ln]) * QSCALE);
        }
    }
    __syncthreads();   // qh published; qstage/Atl dead

    // ---- copy qhat -> Qhs (khalf 0 only); stage K step 0; qf regs ----------
    if (kh == 0) {
        #pragma unroll
        for (int k = 0; k < 2; ++k) {
            int seg = tid * 2 + k, row = seg >> 3, off = (seg & 7) * 8;
            *(shortx8*)&Qhs[((size_t)h * 2048 + n0 + row) * 64 + off] =
                *(shortx8*)&qh[row * 72 + off];
        }
    }
    const int mbase = kh * 1024;
    const int srow = tid >> 2, sc = (tid & 3) * 16;
    #pragma unroll
    for (int i = 0; i < 2; ++i)
        *(shortx8*)(lds + SWZ(srow, sc * 2 + i * 16)) =
            *(const shortx8*)&Kb[(size_t)(mbase + srow) * 64 + sc + i * 8];
    shortx8 qf[2];
    #pragma unroll
    for (int kk = 0; kk < 2; ++kk)
        qf[kk] = *(shortx8*)&qh[(w * 16 + ln) * 72 + kk * 32 + quad * 8];
    __syncthreads();

    // ---- main loop: 16 steps of 64 keys ------------------------------------
    float lacc[4] = {};
    for (int s = 0; s < 16; ++s) {
        const unsigned char* kb = lds + (s & 1) * 8192;
        shortx8 krn[2];
        if (s < 15) {
            int m0n = mbase + (s + 1) * 64;
            #pragma unroll
            for (int i = 0; i < 2; ++i)
                krn[i] = *(const shortx8*)&Kb[(size_t)(m0n + srow) * 64 + sc + i * 8];
        }
        #pragma unroll
        for (int cm = 0; cm < 4; ++cm) {
            shortx8 kf0 = *(const shortx8*)(kb + SWZ(cm * 16 + ln, quad * 16));
            shortx8 kf1 = *(const shortx8*)(kb + SWZ(cm * 16 + ln, 64 + quad * 16));
            floatx4 acc = {};
            acc = __builtin_amdgcn_mfma_f32_16x16x32_bf16(qf[0], kf0, acc, 0, 0, 0);
            acc = __builtin_amdgcn_mfma_f32_16x16x32_bf16(qf[1], kf1, acc, 0, 0, 0);
            #pragma unroll
            for (int r = 0; r < 4; ++r)
                lacc[r] += __builtin_amdgcn_exp2f(acc[r]);
        }
        if (s < 15) {
            unsigned char* kbn = lds + (((s & 1) ^ 1)) * 8192;
            #pragma unroll
            for (int i = 0; i < 2; ++i)
                *(shortx8*)(kbn + SWZ(srow, sc * 2 + i * 16)) = krn[i];
        }
        __syncthreads();
    }

    // ---- epilogue: partial row sums -> atomic l ----------------------------
    #pragma unroll
    for (int r = 0; r < 4; ++r) {
        float x = lacc[r];
        #pragma unroll
        for (int o = 1; o <= 8; o <<= 1) x += __shfl_xor(x, o);
        if (ln == 0)
            atomicAdd(&l_ws[(size_t)h * 2048 + n0 + w * 16 + quad * 4 + r], x);
    }
}

// =================== pass2: g[h,m]=sum_n exp2(qhat.k)/l[n]; fold r ==========
// grid (64,16): blockIdx.x = mtile*2 + nhalf. 64 key-cols (K frags resident),
// 1024 q-rows (16 steps of 64). Qhs-tile dbuf+SWZ + u=1/l inline. Epilogue
// folds partial r = g.values and atomicAdds r_ws.
__global__ __launch_bounds__(256, 4) void pass2_kernel(
    const unsigned short* __restrict__ Qhs, const float* __restrict__ l_ws,
    const unsigned short* __restrict__ Kb, const float* __restrict__ values,
    float* __restrict__ r_ws) {
    const int h = blockIdx.y;
    const int mt = blockIdx.x >> 1, nh = blockIdx.x & 1;
    const int mb = mt * 64;
    const int nbase = nh * 1024;
    const int tid = threadIdx.x;
    const int w = tid >> 6, lane = tid & 63;
    const int ln = lane & 15, quad = lane >> 4;

    __shared__ __align__(16) unsigned char lds[18176];
    // Qbuf[2] @0..16384 (SWZ [64][64]); u_sb[2][64] @16384; g_s @16896;
    // Rred[4][64] @17152
    float* u_sb = (float*)(lds + 16384);
    float* g_s = (float*)(lds + 16896);
    float* Rred = (float*)(lds + 17152);

    shortx8 kf[2];
    #pragma unroll
    for (int kk = 0; kk < 2; ++kk)
        kf[kk] = *(const shortx8*)&Kb[(size_t)(mb + w * 16 + ln) * 64 + kk * 32 + quad * 8];

    const int srow = tid >> 2, sc = (tid & 3) * 16;
    #pragma unroll
    for (int i = 0; i < 2; ++i)
        *(shortx8*)(lds + SWZ(srow, sc * 2 + i * 16)) =
            *(const shortx8*)&Qhs[((size_t)h * 2048 + nbase + srow) * 64 + sc + i * 8];
    if (tid < 64) u_sb[tid] = 1.0f / l_ws[(size_t)h * 2048 + nbase + tid];
    __syncthreads();

    // ---- main loop: 16 steps of 64 q-rows ----------------------------------
    float gacc = 0.f;
    for (int s = 0; s < 16; ++s) {
        const unsigned char* qb = lds + (s & 1) * 8192;
        const float* us = u_sb + (s & 1) * 64;
        shortx8 qrn[2];
        float urn = 0.f;
        if (s < 15) {
            int n0n = nbase + (s + 1) * 64;
            #pragma unroll
            for (int i = 0; i < 2; ++i)
                qrn[i] = *(const shortx8*)&Qhs[((size_t)h * 2048 + n0n + srow) * 64 + sc + i * 8];
            if (tid < 64) urn = 1.0f / l_ws[(size_t)h * 2048 + n0n + tid];
        }
        #pragma unroll
        for (int rt = 0; rt < 4; ++rt) {
            shortx8 qa0 = *(const shortx8*)(qb + SWZ(rt * 16 + ln, quad * 16));
            shortx8 qa1 = *(const shortx8*)(qb + SWZ(rt * 16 + ln, 64 + quad * 16));
            floatx4 acc = {};
            acc = __builtin_amdgcn_mfma_f32_16x16x32_bf16(qa0, kf[0], acc, 0, 0, 0);
            acc = __builtin_amdgcn_mfma_f32_16x16x32_bf16(qa1, kf[1], acc, 0, 0, 0);
            #pragma unroll
            for (int r = 0; r < 4; ++r)
                gacc += __builtin_amdgcn_exp2f(acc[r]) * us[rt * 16 + quad * 4 + r];
        }
        if (s < 15) {
            unsigned char* qbn = lds + (((s & 1) ^ 1)) * 8192;
            #pragma unroll
            for (int i = 0; i < 2; ++i)
                *(shortx8*)(qbn + SWZ(srow, sc * 2 + i * 16)) = qrn[i];
            if (tid < 64) u_sb[((s & 1) ^ 1) * 64 + tid] = urn;
        }
        __syncthreads();
    }

    // ---- column partials g_s, fold partial r = g . values ------------------
    gacc += __shfl_xor(gacc, 16);
    gacc += __shfl_xor(gacc, 32);
    if (quad == 0) g_s[w * 16 + ln] = gacc;   // column m = mb + w*16 + ln
    __syncthreads();
    {
        int grp = tid >> 6, v = tid & 63;
        float acc = 0.f;
        #pragma unroll
        for (int j = 0; j < 16; ++j)
            acc += g_s[grp * 16 + j] *
                   values[(size_t)(mb + grp * 16 + j) * 64 + v];
        Rred[grp * 64 + v] = acc;
    }
    __syncthreads();
    if (tid < 64)
        atomicAdd(&r_ws[h * 64 + tid],
                  Rred[tid] + Rred[64 + tid] + Rred[128 + tid] + Rred[192 + tid]);
}

// =================== pool: pooled[d] = 2048*sum_h bv + sum_hv r*Wv ----------
__global__ __launch_bounds__(256) void pool_kernel(
    const float* __restrict__ Wv, const float* __restrict__ bv,
    const float* __restrict__ r_ws, float* __restrict__ pooled) {
    const int tid = threadIdx.x;
    const int d0 = blockIdx.x * 16;       // grid 64
    const int d = tid & 15, hh = tid >> 4;
    __shared__ float red[16][17];
    float acc = bv[hh * 1024 + d0 + d] * 2048.0f;
    const float* rv = r_ws + hh * 64;
    const float* wp = Wv + (size_t)hh * 64 * 1024 + d0 + d;
    #pragma unroll 8
    for (int v = 0; v < 64; ++v) acc += rv[v] * wp[(size_t)v * 1024];
    red[hh][d] = acc;
    __syncthreads();
    if (tid < 16) {
        float s = 0.f;
        #pragma unroll
        for (int g = 0; g < 16; ++g) s += red[g][tid];
        pooled[d0 + tid] = s;
    }
}

// =================== out: out[dp] = pooled . Wo[dp,:] + bo[dp] ---------------
__global__ __launch_bounds__(256) void out_kernel(
    const float* __restrict__ Wo, const float* __restrict__ bo,
    const float* __restrict__ pooled, float* __restrict__ out) {
    const int tid = threadIdx.x, w = tid >> 6, lane = tid & 63;
    const int dp = blockIdx.x * 4 + w;    // grid 256
    const float* wr = Wo + (size_t)dp * 1024 + lane * 16;
    const float* pp = pooled + lane * 16;
    float acc = 0.f;
    #pragma unroll
    for (int u = 0; u < 4; ++u) {
        float4 a = *(const float4*)&wr[u * 4];
        float4 p = *(const float4*)&pp[u * 4];
        acc += a.x * p.x + a.y * p.y + a.z * p.z + a.w * p.w;
    }
    #pragma unroll
    for (int o = 32; o > 0; o >>= 1) acc += __shfl_xor(acc, o);
    if (lane == 0) out[dp] = acc + bo[dp];
}

extern "C" void kernel_launch(void* const* d_in, const int* in_sizes, int n_in,
                              void* d_out, int out_size, void* d_ws, size_t ws_size,
                              hipStream_t stream) {
    const float* queries = (const float*)d_in[0];
    const float* keys    = (const float*)d_in[1];
    const float* values  = (const float*)d_in[2];
    const float* Wq      = (const float*)d_in[3];
    const float* bq      = (const float*)d_in[4];
    const float* Wk      = (const float*)d_in[5];
    // d_in[6] = bk: row-constant under softmax, unused
    const float* Wv      = (const float*)d_in[7];
    const float* bv      = (const float*)d_in[8];
    const float* Wo      = (const float*)d_in[9];
    const float* bo      = (const float*)d_in[10];
    float* out = (float*)d_out;

    char* base = (char*)d_ws;
    unsigned short* Qhs = (unsigned short*)base;               // 16*2048*64 bf16 = 4MB
    float* l_ws   = (float*)(base + 4194304);                  // 16*2048 f
    float* r_ws   = (float*)(base + 4325376);                  // 1024 f
    float* pooled = (float*)(base + 4329472);                  // 1024 f
    unsigned short* Kb   = (unsigned short*)(base + 4333568);  // 2048*64 bf16
    unsigned short* Atlg = (unsigned short*)(base + 4595712);  // 16*64*64 bf16
    float* vhg    = (float*)(base + 4726784);                  // 16*64 f
    // total ws: ~4.52 MB

    prep_kernel<<<32, 256, 0, stream>>>(Wq, Wk, bq, keys,
                                        Atlg, vhg, Kb, l_ws, r_ws);
    pass1_kernel<<<dim3(64, 16), 256, 0, stream>>>(queries, Atlg, vhg,
                                                   Kb, Qhs, l_ws);
    pass2_kernel<<<dim3(64, 16), 256, 0, stream>>>(Qhs, l_ws, Kb, values, r_ws);
    pool_kernel<<<64, 256, 0, stream>>>(Wv, bv, r_ws, pooled);
    out_kernel<<<256, 256, 0, stream>>>(Wo, bo, pooled, out);
}

// Round 11
// 142.696 us; speedup vs baseline: 1.3976x; 1.3976x over previous
//
#include <hip/hip_runtime.h>

// H=16, DK=DV=64, D=1024, N=M=2048.
// scores[h,n,m] = ((A_h^T q_n + vh_h) . k_m)/8 + row-consts (drop in softmax),
//   A_h[i][j] = sum_d Wq[h,i,d]*Wk[h,j,d],  vh_h[j] = sum_d Wk[h,j,d]*bq[h,d].
// pooled[d] = sum_h sum_v r_h[v]*Wv[h,v,d] + 2048*sum_h bv[h,d],
//   r_h[v] = sum_n softmax_row . V[:,v].   out = pooled @ Wo^T + bo.
// No max-tracking softmax: |s|max ~ 27 << 88 -> exp safe in fp32.
//
// v11 = v7 (best measured total, 132.6) + ONE change: fix v7's measured LDS
// wall (SQ_LDS_BANK_CONFLICT 4.8M cyc ~= 590 cy/CU-step):
//  - K/V LDS tiles: stride-72 rows -> linear [64][64] bf16 + XOR swizzle
//    byte^((row&7)<<4) on staging writes AND fragment reads (v8-proven: 49x
//    conflict reduction; v8's slowdown was its 1-wave/SIMD grid, not the SWZ).
//  - P tile: stride 72 -> 76 (v3's measured-low-conflict layout).
// Everything else verbatim v7: 8 waves x 128 q-rows x 1 head, 32 steps of 64
// keys, dbuf staging, 1 barrier/step, wave-local epilogue.

typedef __attribute__((ext_vector_type(4))) float floatx4;
typedef __attribute__((ext_vector_type(8))) short shortx8;

__device__ inline unsigned short f2bf(float f) {
    unsigned int u = __float_as_uint(f);
    u += 0x7FFFu + ((u >> 16) & 1u);   // RNE
    return (unsigned short)(u >> 16);
}
__device__ inline float bf2f(unsigned short s) {
    return __uint_as_float(((unsigned int)s) << 16);
}

// byte offset into a [64][64]-bf16 LDS tile, bank-conflict-free (v8-proven):
#define SWZ(row, bc) ((row) * 128 + ((bc) ^ (((row) & 7) << 4)))

// =================== prep: fused A-partials / K-cvt / V-transpose ============
// grid 176: blocks 0-127: (g,h) A-partial + vh-partial via MFMA (k-chunk 128)
//           blocks 128-143: K bf16 convert (linear) + r zero
//           blocks 144-175: V transpose -> VT bf16 (linear [64][2048])
__global__ __launch_bounds__(256) void prep_kernel(
    const float* __restrict__ Wq, const float* __restrict__ Wk,
    const float* __restrict__ bq, const float* __restrict__ keys,
    const float* __restrict__ values,
    float* __restrict__ Apart, float* __restrict__ vhpart,
    unsigned short* __restrict__ Kb, unsigned short* __restrict__ VT,
    float* __restrict__ r_ws) {
    const int tid = threadIdx.x;
    const int bx = blockIdx.x;
    __shared__ __align__(16) unsigned char sm[36352];
    if (bx < 128) {
        const int g = bx >> 4, h = bx & 15;
        const int c0 = g * 128;
        unsigned short* wq = (unsigned short*)sm;            // 64*136 ushort
        unsigned short* wk = (unsigned short*)(sm + 17408);  // 64*136 ushort
        float* bqs = (float*)(sm + 34816);                   // 128
        float* vred = (float*)(sm + 35328);                  // 4*64
        {
            int row = tid >> 2, cs = (tid & 3) * 32;
            const float* wqp = Wq + (size_t)(h * 64 + row) * 1024 + c0 + cs;
            const float* wkp = Wk + (size_t)(h * 64 + row) * 1024 + c0 + cs;
            #pragma unroll
            for (int u = 0; u < 8; ++u) {
                float4 a = *(const float4*)&wqp[u * 4];
                float4 b = *(const float4*)&wkp[u * 4];
                *(ushort4*)&wq[row * 136 + cs + u * 4] =
                    (ushort4){f2bf(a.x), f2bf(a.y), f2bf(a.z), f2bf(a.w)};
                *(ushort4*)&wk[row * 136 + cs + u * 4] =
                    (ushort4){f2bf(b.x), f2bf(b.y), f2bf(b.z), f2bf(b.w)};
            }
            if (tid < 128) bqs[tid] = bq[h * 1024 + c0 + tid];
        }
        __syncthreads();
        const int w = tid >> 6, lane = tid & 63;
        const int ln = lane & 15, quad = lane >> 4;
        {   // vh partial
            const int j = tid & 63, half = tid >> 6;
            float accv = 0.f;
            #pragma unroll
            for (int u = 0; u < 32; ++u)
                accv += bf2f(wk[j * 136 + half * 32 + u]) * bqs[half * 32 + u];
            vred[half * 64 + j] = accv;
        }
        // A-tile: wave w -> rows w*16..+15
        shortx8 af[4];
        #pragma unroll
        for (int kk = 0; kk < 4; ++kk)
            af[kk] = *(shortx8*)&wq[(w * 16 + ln) * 136 + kk * 32 + quad * 8];
        float* ap = Apart + (size_t)bx * 4096;
        #pragma unroll
        for (int cn = 0; cn < 4; ++cn) {
            floatx4 acc = {};
            #pragma unroll
            for (int kk = 0; kk < 4; ++kk) {
                shortx8 bf_ = *(shortx8*)&wk[(cn * 16 + ln) * 136 + kk * 32 + quad * 8];
                acc = __builtin_amdgcn_mfma_f32_16x16x32_bf16(af[kk], bf_, acc, 0, 0, 0);
            }
            #pragma unroll
            for (int r = 0; r < 4; ++r)
                ap[(w * 16 + quad * 4 + r) * 64 + cn * 16 + ln] = acc[r];
        }
        __syncthreads();
        if (tid < 64)
            vhpart[bx * 64 + tid] = vred[tid] + vred[64 + tid] +
                                    vred[128 + tid] + vred[192 + tid];
    } else if (bx < 144) {
        int bk = bx - 128;
        int base = (bk * 256 + tid) * 32;
        #pragma unroll
        for (int u = 0; u < 8; ++u) {
            float4 a = *(const float4*)&keys[base + u * 4];
            *(ushort4*)&Kb[base + u * 4] =
                (ushort4){f2bf(a.x), f2bf(a.y), f2bf(a.z), f2bf(a.w)};
        }
        if (tid < 64) r_ws[bk * 64 + tid] = 0.f;
    } else {
        int bb = bx - 144, m0 = bb * 64;
        unsigned short* vts = (unsigned short*)sm;   // 64*72 ushort
        #pragma unroll
        for (int it = 0; it < 4; ++it) {
            int gi = tid + it * 256;
            int m = gi >> 4, c4 = (gi & 15) * 4;
            float4 a = *(const float4*)&values[(size_t)(m0 + m) * 64 + c4];
            vts[(c4 + 0) * 72 + m] = f2bf(a.x);
            vts[(c4 + 1) * 72 + m] = f2bf(a.y);
            vts[(c4 + 2) * 72 + m] = f2bf(a.z);
            vts[(c4 + 3) * 72 + m] = f2bf(a.w);
        }
        __syncthreads();
        #pragma unroll
        for (int it = 0; it < 2; ++it) {
            int gi = tid + it * 256;
            int v = gi >> 3, seg = (gi & 7) * 8;
            *(shortx8*)&VT[v * 2048 + m0 + seg] = *(shortx8*)&vts[v * 72 + seg];
        }
    }
}

// =================== reduceA: sum 8 A-partials -> Atlg (A^T, bf16), vhg ======
__global__ __launch_bounds__(256) void reduceA_kernel(
    const float* __restrict__ Apart, const float* __restrict__ vhpart,
    unsigned short* __restrict__ Atlg, float* __restrict__ vhg) {
    const int tid = threadIdx.x;
    const int h = blockIdx.x >> 2, uq = blockIdx.x & 3;
    #pragma unroll
    for (int uu = 0; uu < 4; ++uu) {
        int e = (uq * 4 + uu) * 256 + tid;     // e = i*64 + j
        float s = 0.f;
        #pragma unroll
        for (int g = 0; g < 8; ++g)
            s += Apart[g * 65536 + h * 4096 + e];
        Atlg[h * 4096 + (e & 63) * 64 + (e >> 6)] = f2bf(s);   // A^T[j][i]
    }
    if (uq == 0 && tid < 64) {
        float s = 0.f;
        #pragma unroll
        for (int g = 0; g < 8; ++g) s += vhpart[(g * 16 + h) * 64 + tid];
        vhg[h * 64 + tid] = s;
    }
}

// =================== flash v11: grid (16 qtiles of 128 rows, 16 h) ===========
// 512 threads = 8 waves; wave w owns rows n0+w*16..+15. 32 steps of 64 keys.
// Per step: K-tile + V-tile ([64][64] bf16, XOR-swizzled) staged into dbuf
// LDS by all threads, consumed by all 8 waves. 1 barrier/step.
#define QSCALE 0.18033688f   /* 0.125 * log2(e) */
__global__ __launch_bounds__(512, 2) void flash_kernel(
    const float* __restrict__ queries, const unsigned short* __restrict__ Atlg,
    const float* __restrict__ vhg, const unsigned short* __restrict__ Kb,
    const unsigned short* __restrict__ VT, float* __restrict__ r_ws) {
    const int h = blockIdx.y;
    const int n0 = blockIdx.x * 128;
    const int tid = threadIdx.x;
    const int w = tid >> 6, lane = tid & 63;
    const int ln = lane & 15, quad = lane >> 4;

    __shared__ __align__(16) unsigned char lds[70656];
    __shared__ float vhs[64];
    // main loop: Kbuf[2] @0/@8192 ; Vbuf[2] @16384/@24576 (SWZ [64][64] each)
    //            qh @32768 ([128][72] shorts = 18432B, ends 51200)
    //            Pw @51200 + w*2432 ([16][76] shorts per wave, ends 70656)
    // phase A/B: qstage @0 ([128][72]=18432B), Atl @18432 (9216B) -- both dead
    //            before K/V staging overwrites them (barrier-ordered).
    // epilogue:  Rred @0 (8*64 f32) after final barrier.
    unsigned short* qh   = (unsigned short*)(lds + 32768);
    unsigned short* Pw   = (unsigned short*)(lds + 51200 + w * 2432);
    unsigned short* qstage = (unsigned short*)lds;
    unsigned short* Atl  = (unsigned short*)(lds + 18432);
    float* Rred = (float*)lds;

    // ---- phase A: stage queries (bf16) [128][72], Atl (8KB coalesced), vhs -
    {
        int row = tid >> 2, c16 = (tid & 3) * 16;
        const float* qp = queries + (size_t)(n0 + row) * 64 + c16;
        #pragma unroll
        for (int u = 0; u < 4; ++u) {
            float4 a = *(const float4*)&qp[u * 4];
            *(ushort4*)&qstage[row * 72 + c16 + u * 4] =
                (ushort4){f2bf(a.x), f2bf(a.y), f2bf(a.z), f2bf(a.w)};
        }
    }
    {
        int row = tid >> 3, off = (tid & 7) * 8;
        *(shortx8*)&Atl[row * 72 + off] =
            *(const shortx8*)&Atlg[h * 4096 + row * 64 + off];
    }
    if (tid < 64) vhs[tid] = vhg[h * 64 + tid];
    __syncthreads();

    // ---- phase B: qhat = (q.A^T + vh)*scale; wave w -> rows w*16..+15 ------
    {
        shortx8 qa[2];
        #pragma unroll
        for (int kk = 0; kk < 2; ++kk)
            qa[kk] = *(shortx8*)&qstage[(w * 16 + ln) * 72 + kk * 32 + quad * 8];
        #pragma unroll
        for (int cn = 0; cn < 4; ++cn) {
            floatx4 acc = {};
            #pragma unroll
            for (int kk = 0; kk < 2; ++kk) {
                shortx8 bfr = *(shortx8*)&Atl[(cn * 16 + ln) * 72 + kk * 32 + quad * 8];
                acc = __builtin_amdgcn_mfma_f32_16x16x32_bf16(qa[kk], bfr, acc, 0, 0, 0);
            }
            #pragma unroll
            for (int r = 0; r < 4; ++r)
                qh[(w * 16 + quad * 4 + r) * 72 + cn * 16 + ln] =
                    f2bf((acc[r] + vhs[cn * 16 + ln]) * QSCALE);
        }
    }
    __syncthreads();   // qstage/Atl dead -> staging may overwrite lds[0..32767]

    // ---- prologue: stage step-0 K/V tiles (swizzled) -----------------------
    const int srow = tid >> 3, scol = (tid & 7) * 8;   // 64 rows x 8 segs
    {
        shortx8 kr = *(const shortx8*)&Kb[(size_t)srow * 64 + scol];
        shortx8 vr = *(const shortx8*)&VT[srow * 2048 + scol];
        *(shortx8*)(lds + SWZ(srow, scol * 2)) = kr;            // Kbuf[0]
        *(shortx8*)(lds + 16384 + SWZ(srow, scol * 2)) = vr;    // Vbuf[0]
    }
    // qf: own wave wrote its qh rows (lgkm-ordered); read A-frag
    shortx8 qf[2];
    #pragma unroll
    for (int kk = 0; kk < 2; ++kk)
        qf[kk] = *(shortx8*)&qh[(w * 16 + ln) * 72 + kk * 32 + quad * 8];
    __syncthreads();

    // ---- main loop: 32 steps of 64 keys, 1 barrier/step --------------------
    floatx4 O[4] = {};
    float lacc[4] = {};
    for (int s = 0; s < 32; ++s) {
        const int b = s & 1;
        const unsigned char* kb = lds + b * 8192;
        const unsigned char* vb = lds + 16384 + b * 8192;
        // issue next-step staging loads (consumed at step end: latency hidden)
        shortx8 krn, vrn;
        if (s < 31) {
            int m0n = (s + 1) * 64;
            krn = *(const shortx8*)&Kb[(size_t)(m0n + srow) * 64 + scol];
            vrn = *(const shortx8*)&VT[srow * 2048 + m0n + scol];
        }
        // QK: S[cm] = qhat_tile . K_tile^T
        floatx4 S[4];
        #pragma unroll
        for (int cm = 0; cm < 4; ++cm) {
            shortx8 kf0 = *(const shortx8*)(kb + SWZ(cm * 16 + ln, quad * 16));
            shortx8 kf1 = *(const shortx8*)(kb + SWZ(cm * 16 + ln, 64 + quad * 16));
            floatx4 acc = {};
            acc = __builtin_amdgcn_mfma_f32_16x16x32_bf16(qf[0], kf0, acc, 0, 0, 0);
            acc = __builtin_amdgcn_mfma_f32_16x16x32_bf16(qf[1], kf1, acc, 0, 0, 0);
            S[cm] = acc;
        }
        // exp2 + P (wave-private LDS, stride 76)
        #pragma unroll
        for (int cm = 0; cm < 4; ++cm) {
            #pragma unroll
            for (int r = 0; r < 4; ++r) {
                float p = __builtin_amdgcn_exp2f(S[cm][r]);
                lacc[r] += p;
                Pw[(quad * 4 + r) * 76 + cm * 16 + ln] = f2bf(p);
            }
        }
        // P frags (same wave wrote them: lgkm ordering, no barrier)
        shortx8 pf[2];
        #pragma unroll
        for (int kk = 0; kk < 2; ++kk)
            pf[kk] = *(shortx8*)&Pw[ln * 76 + kk * 32 + quad * 8];
        // PV (swizzled V frags)
        #pragma unroll
        for (int cv = 0; cv < 4; ++cv) {
            shortx8 v0 = *(const shortx8*)(vb + SWZ(cv * 16 + ln, quad * 16));
            shortx8 v1 = *(const shortx8*)(vb + SWZ(cv * 16 + ln, 64 + quad * 16));
            O[cv] = __builtin_amdgcn_mfma_f32_16x16x32_bf16(pf[0], v0, O[cv], 0, 0, 0);
            O[cv] = __builtin_amdgcn_mfma_f32_16x16x32_bf16(pf[1], v1, O[cv], 0, 0, 0);
        }
        // publish next-step tiles into the other buffer (its readers finished
        // at the previous barrier), then barrier releases everyone into s+1
        if (s < 31) {
            *(shortx8*)(lds + (b ^ 1) * 8192 + SWZ(srow, scol * 2)) = krn;
            *(shortx8*)(lds + 16384 + (b ^ 1) * 8192 + SWZ(srow, scol * 2)) = vrn;
        }
        __syncthreads();
    }

    // ---- epilogue: wave-local row sums + normalize + r accumulate ----------
    float linv[4];
    #pragma unroll
    for (int r = 0; r < 4; ++r) {
        float x = lacc[r];
        #pragma unroll
        for (int o = 1; o <= 8; o <<= 1) x += __shfl_xor(x, o);
        linv[r] = 1.0f / x;   // row w*16+quad*4+r full sum (all 2048 keys)
    }
    float sacc[4];
    #pragma unroll
    for (int cv = 0; cv < 4; ++cv) {
        float s = 0.f;
        #pragma unroll
        for (int r = 0; r < 4; ++r) s += O[cv][r] * linv[r];
        s += __shfl_xor(s, 16);
        s += __shfl_xor(s, 32);
        sacc[cv] = s;          // sum over the wave's 16 rows, col cv*16+ln
    }
    __syncthreads();           // K/V/P buffers dead -> Rred overlay
    if (quad == 0) {
        #pragma unroll
        for (int cv = 0; cv < 4; ++cv)
            Rred[w * 64 + cv * 16 + ln] = sacc[cv];
    }
    __syncthreads();
    if (tid < 64) {
        float s = 0.f;
        #pragma unroll
        for (int g = 0; g < 8; ++g) s += Rred[g * 64 + tid];
        atomicAdd(&r_ws[h * 64 + tid], s);
    }
}

// =================== pool: pooled[d] = 2048*sum_h bv + sum_hv r*Wv ----------
__global__ __launch_bounds__(256) void pool_kernel(
    const float* __restrict__ Wv, const float* __restrict__ bv,
    const float* __restrict__ r_ws, float* __restrict__ pooled) {
    const int tid = threadIdx.x;
    const int d0 = blockIdx.x * 16;       // grid 64
    const int d = tid & 15, hh = tid >> 4;
    __shared__ float red[16][17];
    float acc = bv[hh * 1024 + d0 + d] * 2048.0f;
    const float* rv = r_ws + hh * 64;
    const float* wp = Wv + (size_t)hh * 64 * 1024 + d0 + d;
    #pragma unroll 8
    for (int v = 0; v < 64; ++v) acc += rv[v] * wp[(size_t)v * 1024];
    red[hh][d] = acc;
    __syncthreads();
    if (tid < 16) {
        float s = 0.f;
        #pragma unroll
        for (int g = 0; g < 16; ++g) s += red[g][tid];
        pooled[d0 + tid] = s;
    }
}

// =================== out: out[dp] = pooled . Wo[dp,:] + bo[dp] ---------------
__global__ __launch_bounds__(256) void out_kernel(
    const float* __restrict__ Wo, const float* __restrict__ bo,
    const float* __restrict__ pooled, float* __restrict__ out) {
    const int tid = threadIdx.x, w = tid >> 6, lane = tid & 63;
    const int dp = blockIdx.x * 4 + w;    // grid 256
    const float* wr = Wo + (size_t)dp * 1024 + lane * 16;
    const float* pp = pooled + lane * 16;
    float acc = 0.f;
    #pragma unroll
    for (int u = 0; u < 4; ++u) {
        float4 a = *(const float4*)&wr[u * 4];
        float4 p = *(const float4*)&pp[u * 4];
        acc += a.x * p.x + a.y * p.y + a.z * p.z + a.w * p.w;
    }
    #pragma unroll
    for (int o = 32; o > 0; o >>= 1) acc += __shfl_xor(acc, o);
    if (lane == 0) out[dp] = acc + bo[dp];
}

extern "C" void kernel_launch(void* const* d_in, const int* in_sizes, int n_in,
                              void* d_out, int out_size, void* d_ws, size_t ws_size,
                              hipStream_t stream) {
    const float* queries = (const float*)d_in[0];
    const float* keys    = (const float*)d_in[1];
    const float* values  = (const float*)d_in[2];
    const float* Wq      = (const float*)d_in[3];
    const float* bq      = (const float*)d_in[4];
    const float* Wk      = (const float*)d_in[5];
    // d_in[6] = bk: row-constant under softmax, unused
    const float* Wv      = (const float*)d_in[7];
    const float* bv      = (const float*)d_in[8];
    const float* Wo      = (const float*)d_in[9];
    const float* bo      = (const float*)d_in[10];
    float* out = (float*)d_out;

    float* Apart  = (float*)d_ws;                 // 128*4096 floats
    float* vhpart = Apart + 524288;               // 128*64
    float* r_ws   = vhpart + 8192;                // 1024
    float* pooled = r_ws + 1024;                  // 1024
    unsigned short* Kb = (unsigned short*)(pooled + 1024);  // 2048*64 bf16
    unsigned short* VT = Kb + 131072;                       // 64*2048 bf16
    unsigned short* Atlg = VT + 131072;                     // 16*64*64 bf16
    float* vhg = (float*)(Atlg + 65536);                    // 16*64
    // total ws: ~2.8 MB

    prep_kernel<<<176, 256, 0, stream>>>(Wq, Wk, bq, keys, values,
                                         Apart, vhpart, Kb, VT, r_ws);
    reduceA_kernel<<<64, 256, 0, stream>>>(Apart, vhpart, Atlg, vhg);
    flash_kernel<<<dim3(16, 16), 512, 0, stream>>>(queries, Atlg, vhg,
                                                   Kb, VT, r_ws);
    pool_kernel<<<64, 256, 0, stream>>>(Wv, bv, r_ws, pooled);
    out_kernel<<<256, 256, 0, stream>>>(Wo, bo, pooled, out);
}

// Round 12
// 134.115 us; speedup vs baseline: 1.4870x; 1.0640x over previous
//
#include <hip/hip_runtime.h>

// H=16, DK=DV=64, D=1024, N=M=2048.
// scores[h,n,m] = ((A_h^T q_n + vh_h) . k_m)/8 + row-consts (drop in softmax),
//   A_h[i][j] = sum_d Wq[h,i,d]*Wk[h,j,d],  vh_h[j] = sum_d Wk[h,j,d]*bq[h,d].
// r_h[v] = sum_m g_h[m]*values[m,v],  g_h[m] = sum_n exp(s[n,m])/l[n],
// l[n] = sum_m exp(s[n,m]).  pooled = r.Wv + 2048*sum_h bv; out = pooled.Wo^T+bo.
// No max-tracking: |s|max ~ 27 << 88 -> exp2 safe in fp32.
//
// v12 = v9 (two-pass, passed @137.7) + ONE change: TRIPLE-buffered staging
// (stage-ahead 2) in pass1/pass2. v9's steps are ~500cy and its dbuf gave
// the staging load only end-of-step cover ~= L2 latency -> every step ate
// exposed latency (passes ~29us vs 12.8us LDS floor). Now the load for tile
// s+2 is issued at step s and consumed (ds_write) at step s+1 top: a full
// step of cover. Hazards: write buf[(s+1)%3]=(s-2)%3 readers done at
// barrier(s-2); readers of buf[s%3] start after barrier(s-1). Everything
// else byte-identical v9 (lesson of v10: one variable).

typedef __attribute__((ext_vector_type(4))) float floatx4;
typedef __attribute__((ext_vector_type(8))) short shortx8;

__device__ inline unsigned short f2bf(float f) {
    unsigned int u = __float_as_uint(f);
    u += 0x7FFFu + ((u >> 16) & 1u);   // RNE
    return (unsigned short)(u >> 16);
}
__device__ inline float bf2f(unsigned short s) {
    return __uint_as_float(((unsigned int)s) << 16);
}

#define SWZ(row, bc) ((row) * 128 + ((bc) ^ (((row) & 7) << 4)))
#define QSCALE 0.18033688f   /* 0.125 * log2(e) */

// =================== prep: fused A-partials / K-cvt =========================
// grid 144: blocks 0-127: (g,h) A-partial + vh-partial via MFMA (k-chunk 128)
//           blocks 128-143: K bf16 convert (linear) + r zero
__global__ __launch_bounds__(256) void prep_kernel(
    const float* __restrict__ Wq, const float* __restrict__ Wk,
    const float* __restrict__ bq, const float* __restrict__ keys,
    float* __restrict__ Apart, float* __restrict__ vhpart,
    unsigned short* __restrict__ Kb, float* __restrict__ r_ws) {
    const int tid = threadIdx.x;
    const int bx = blockIdx.x;
    __shared__ __align__(16) unsigned char sm[36352];
    if (bx < 128) {
        const int g = bx >> 4, h = bx & 15;
        const int c0 = g * 128;
        unsigned short* wq = (unsigned short*)sm;            // 64*136 ushort
        unsigned short* wk = (unsigned short*)(sm + 17408);  // 64*136 ushort
        float* bqs = (float*)(sm + 34816);                   // 128
        float* vred = (float*)(sm + 35328);                  // 4*64
        {
            int row = tid >> 2, cs = (tid & 3) * 32;
            const float* wqp = Wq + (size_t)(h * 64 + row) * 1024 + c0 + cs;
            const float* wkp = Wk + (size_t)(h * 64 + row) * 1024 + c0 + cs;
            #pragma unroll
            for (int u = 0; u < 8; ++u) {
                float4 a = *(const float4*)&wqp[u * 4];
                float4 b = *(const float4*)&wkp[u * 4];
                *(ushort4*)&wq[row * 136 + cs + u * 4] =
                    (ushort4){f2bf(a.x), f2bf(a.y), f2bf(a.z), f2bf(a.w)};
                *(ushort4*)&wk[row * 136 + cs + u * 4] =
                    (ushort4){f2bf(b.x), f2bf(b.y), f2bf(b.z), f2bf(b.w)};
            }
            if (tid < 128) bqs[tid] = bq[h * 1024 + c0 + tid];
        }
        __syncthreads();
        const int w = tid >> 6, lane = tid & 63;
        const int ln = lane & 15, quad = lane >> 4;
        {   // vh partial
            const int j = tid & 63, half = tid >> 6;
            float accv = 0.f;
            #pragma unroll
            for (int u = 0; u < 32; ++u)
                accv += bf2f(wk[j * 136 + half * 32 + u]) * bqs[half * 32 + u];
            vred[half * 64 + j] = accv;
        }
        // A-tile: wave w -> rows w*16..+15
        shortx8 af[4];
        #pragma unroll
        for (int kk = 0; kk < 4; ++kk)
            af[kk] = *(shortx8*)&wq[(w * 16 + ln) * 136 + kk * 32 + quad * 8];
        float* ap = Apart + (size_t)bx * 4096;
        #pragma unroll
        for (int cn = 0; cn < 4; ++cn) {
            floatx4 acc = {};
            #pragma unroll
            for (int kk = 0; kk < 4; ++kk) {
                shortx8 bf_ = *(shortx8*)&wk[(cn * 16 + ln) * 136 + kk * 32 + quad * 8];
                acc = __builtin_amdgcn_mfma_f32_16x16x32_bf16(af[kk], bf_, acc, 0, 0, 0);
            }
            #pragma unroll
            for (int r = 0; r < 4; ++r)
                ap[(w * 16 + quad * 4 + r) * 64 + cn * 16 + ln] = acc[r];
        }
        __syncthreads();
        if (tid < 64)
            vhpart[bx * 64 + tid] = vred[tid] + vred[64 + tid] +
                                    vred[128 + tid] + vred[192 + tid];
    } else {
        int bk = bx - 128;
        int base = (bk * 256 + tid) * 32;
        #pragma unroll
        for (int u = 0; u < 8; ++u) {
            float4 a = *(const float4*)&keys[base + u * 4];
            *(ushort4*)&Kb[base + u * 4] =
                (ushort4){f2bf(a.x), f2bf(a.y), f2bf(a.z), f2bf(a.w)};
        }
        if (tid < 64) r_ws[bk * 64 + tid] = 0.f;
    }
}

// =================== reduceA: sum 8 A-partials -> Atlg (A^T, bf16), vhg ======
__global__ __launch_bounds__(256) void reduceA_kernel(
    const float* __restrict__ Apart, const float* __restrict__ vhpart,
    unsigned short* __restrict__ Atlg, float* __restrict__ vhg) {
    const int tid = threadIdx.x;
    const int h = blockIdx.x >> 2, uq = blockIdx.x & 3;
    #pragma unroll
    for (int uu = 0; uu < 4; ++uu) {
        int e = (uq * 4 + uu) * 256 + tid;     // e = i*64 + j
        float s = 0.f;
        #pragma unroll
        for (int g = 0; g < 8; ++g)
            s += Apart[g * 65536 + h * 4096 + e];
        Atlg[h * 4096 + (e & 63) * 64 + (e >> 6)] = f2bf(s);   // A^T[j][i]
    }
    if (uq == 0 && tid < 64) {
        float s = 0.f;
        #pragma unroll
        for (int g = 0; g < 8; ++g) s += vhpart[(g * 16 + h) * 64 + tid];
        vhg[h * 64 + tid] = s;
    }
}

// =================== pass1: u[h,n] = 1/sum_m exp2(qhat.k) ====================
// grid (32 ntiles of 64 rows, 16 h), 256 thr = 4 waves; wave w -> rows
// w*16..+15. Writes Qhs. 32 steps of 64 keys, K-tiles in 3-deep staged LDS.
__global__ __launch_bounds__(256, 4) void pass1_kernel(
    const float* __restrict__ queries, const unsigned short* __restrict__ Atlg,
    const float* __restrict__ vhg, const unsigned short* __restrict__ Kb,
    unsigned short* __restrict__ Qhs, float* __restrict__ u_ws) {
    const int h = blockIdx.y;
    const int n0 = blockIdx.x * 64;
    const int tid = threadIdx.x;
    const int w = tid >> 6, lane = tid & 63;
    const int ln = lane & 15, quad = lane >> 4;

    __shared__ __align__(16) unsigned char lds[33792];
    __shared__ float vhs[64];
    // phase A: qstage @0 (9216), Atl @9216 (9216, ends 18432) -- die at loop
    // loop:    Kbuf[3] @0/@8192/@16384 (SWZ [64][64]), qh @24576 ([64][72])
    unsigned short* qstage = (unsigned short*)lds;
    unsigned short* Atl = (unsigned short*)(lds + 9216);
    unsigned short* qh = (unsigned short*)(lds + 24576);

    // ---- phase A: stage queries (bf16), Atl (coalesced), vhs ---------------
    {
        int row = tid >> 2, c16 = (tid & 3) * 16;
        const float* qp = queries + (size_t)(n0 + row) * 64 + c16;
        #pragma unroll
        for (int u = 0; u < 4; ++u) {
            float4 a = *(const float4*)&qp[u * 4];
            *(ushort4*)&qstage[row * 72 + c16 + u * 4] =
                (ushort4){f2bf(a.x), f2bf(a.y), f2bf(a.z), f2bf(a.w)};
        }
        #pragma unroll
        for (int u = 0; u < 2; ++u)
            *(shortx8*)&Atl[row * 72 + c16 + u * 8] =
                *(const shortx8*)&Atlg[h * 4096 + row * 64 + c16 + u * 8];
    }
    if (tid < 64) vhs[tid] = vhg[h * 64 + tid];
    __syncthreads();

    // ---- phase B: qhat via MFMA; wave w -> rowtile w -----------------------
    {
        shortx8 qa[2];
        #pragma unroll
        for (int kk = 0; kk < 2; ++kk)
            qa[kk] = *(shortx8*)&qstage[(w * 16 + ln) * 72 + kk * 32 + quad * 8];
        #pragma unroll
        for (int cn = 0; cn < 4; ++cn) {
            floatx4 acc = {};
            #pragma unroll
            for (int kk = 0; kk < 2; ++kk) {
                shortx8 bfr = *(shortx8*)&Atl[(cn * 16 + ln) * 72 + kk * 32 + quad * 8];
                acc = __builtin_amdgcn_mfma_f32_16x16x32_bf16(qa[kk], bfr, acc, 0, 0, 0);
            }
            #pragma unroll
            for (int r = 0; r < 4; ++r)
                qh[(w * 16 + quad * 4 + r) * 72 + cn * 16 + ln] =
                    f2bf((acc[r] + vhs[cn * 16 + ln]) * QSCALE);
        }
    }
    __syncthreads();   // qh published; qstage/Atl dead

    // ---- prologue: Qhs copy; stage s0 into buf0; preload s1 regs; qf -------
    #pragma unroll
    for (int k = 0; k < 2; ++k) {
        int seg = tid * 2 + k, row = seg >> 3, off = (seg & 7) * 8;
        *(shortx8*)&Qhs[((size_t)h * 2048 + n0 + row) * 64 + off] =
            *(shortx8*)&qh[row * 72 + off];
    }
    const int srow = tid >> 2, sc = (tid & 3) * 16;
    #pragma unroll
    for (int i = 0; i < 2; ++i)
        *(shortx8*)(lds + SWZ(srow, sc * 2 + i * 16)) =
            *(const shortx8*)&Kb[(size_t)srow * 64 + sc + i * 8];
    shortx8 kr[2];
    #pragma unroll
    for (int i = 0; i < 2; ++i)
        kr[i] = *(const shortx8*)&Kb[(size_t)(64 + srow) * 64 + sc + i * 8];
    shortx8 qf[2];
    #pragma unroll
    for (int kk = 0; kk < 2; ++kk)
        qf[kk] = *(shortx8*)&qh[(w * 16 + ln) * 72 + kk * 32 + quad * 8];
    __syncthreads();

    // ---- main loop: 32 steps of 64 keys, 3-deep staging --------------------
    float lacc[4] = {};
    int rb = 0;
    for (int s = 0; s < 32; ++s) {
        const unsigned char* kb = lds + rb * 8192;
        const int wb = (rb == 2) ? 0 : rb + 1;
        if (s < 31) {          // publish tile s+1 (buf last read at step s-2)
            #pragma unroll
            for (int i = 0; i < 2; ++i)
                *(shortx8*)(lds + wb * 8192 + SWZ(srow, sc * 2 + i * 16)) = kr[i];
        }
        if (s < 30) {          // issue tile s+2 (consumed at step s+1 top)
            int m0n = (s + 2) * 64;
            #pragma unroll
            for (int i = 0; i < 2; ++i)
                kr[i] = *(const shortx8*)&Kb[(size_t)(m0n + srow) * 64 + sc + i * 8];
        }
        #pragma unroll
        for (int cm = 0; cm < 4; ++cm) {
            shortx8 kf0 = *(const shortx8*)(kb + SWZ(cm * 16 + ln, quad * 16));
            shortx8 kf1 = *(const shortx8*)(kb + SWZ(cm * 16 + ln, 64 + quad * 16));
            floatx4 acc = {};
            acc = __builtin_amdgcn_mfma_f32_16x16x32_bf16(qf[0], kf0, acc, 0, 0, 0);
            acc = __builtin_amdgcn_mfma_f32_16x16x32_bf16(qf[1], kf1, acc, 0, 0, 0);
            #pragma unroll
            for (int r = 0; r < 4; ++r)
                lacc[r] += __builtin_amdgcn_exp2f(acc[r]);
        }
        __syncthreads();
        rb = wb;
    }

    // ---- epilogue: row sums over ln-group, write u = 1/l -------------------
    #pragma unroll
    for (int r = 0; r < 4; ++r) {
        float x = lacc[r];
        #pragma unroll
        for (int o = 1; o <= 8; o <<= 1) x += __shfl_xor(x, o);
        if (ln == 0)
            u_ws[(size_t)h * 2048 + n0 + w * 16 + quad * 4 + r] = 1.0f / x;
    }
}

// =================== pass2: g[h,m]=sum_n exp2(qhat.k)*u[n]; fold r ==========
// grid (32 mtiles of 64 keys, 16 h), 256 thr = 4 waves; wave w -> key columns
// mb+w*16..+15 (K frags resident). 32 steps of 64 q-rows, Qhs-tiles in
// 3-deep staged LDS (+u). Epilogue folds r = g.values, atomicAdds r_ws.
__global__ __launch_bounds__(256, 4) void pass2_kernel(
    const unsigned short* __restrict__ Qhs, const float* __restrict__ u_ws,
    const unsigned short* __restrict__ Kb, const float* __restrict__ values,
    float* __restrict__ r_ws) {
    const int h = blockIdx.y;
    const int mb = blockIdx.x * 64;
    const int tid = threadIdx.x;
    const int w = tid >> 6, lane = tid & 63;
    const int ln = lane & 15, quad = lane >> 4;

    __shared__ __align__(16) unsigned char lds[26624];
    // Qbuf[3] @0..24576 (SWZ [64][64]); u_sb[3][64] f32 @24576 (768);
    // g_s[64] @25344; Rred[4][64] @25600
    float* u_sb = (float*)(lds + 24576);
    float* g_s = (float*)(lds + 25344);
    float* Rred = (float*)(lds + 25600);

    // K frags for this wave's 16 columns (resident)
    shortx8 kf[2];
    #pragma unroll
    for (int kk = 0; kk < 2; ++kk)
        kf[kk] = *(const shortx8*)&Kb[(size_t)(mb + w * 16 + ln) * 64 + kk * 32 + quad * 8];

    // stage s0 (q-rows 0..63) + u0; preload s1 regs
    const int srow = tid >> 2, sc = (tid & 3) * 16;
    #pragma unroll
    for (int i = 0; i < 2; ++i)
        *(shortx8*)(lds + SWZ(srow, sc * 2 + i * 16)) =
            *(const shortx8*)&Qhs[((size_t)h * 2048 + srow) * 64 + sc + i * 8];
    if (tid < 64) u_sb[tid] = u_ws[(size_t)h * 2048 + tid];
    shortx8 qrn[2];
    float urn = 0.f;
    #pragma unroll
    for (int i = 0; i < 2; ++i)
        qrn[i] = *(const shortx8*)&Qhs[((size_t)h * 2048 + 64 + srow) * 64 + sc + i * 8];
    if (tid < 64) urn = u_ws[(size_t)h * 2048 + 64 + tid];
    __syncthreads();

    // ---- main loop: 32 steps of 64 q-rows, 3-deep staging ------------------
    float gacc = 0.f;
    int rb = 0;
    for (int s = 0; s < 32; ++s) {
        const unsigned char* qb = lds + rb * 8192;
        const float* us = u_sb + rb * 64;
        const int wb = (rb == 2) ? 0 : rb + 1;
        if (s < 31) {          // publish tile s+1
            #pragma unroll
            for (int i = 0; i < 2; ++i)
                *(shortx8*)(lds + wb * 8192 + SWZ(srow, sc * 2 + i * 16)) = qrn[i];
            if (tid < 64) u_sb[wb * 64 + tid] = urn;
        }
        if (s < 30) {          // issue tile s+2
            int n0n = (s + 2) * 64;
            #pragma unroll
            for (int i = 0; i < 2; ++i)
                qrn[i] = *(const shortx8*)&Qhs[((size_t)h * 2048 + n0n + srow) * 64 + sc + i * 8];
            if (tid < 64) urn = u_ws[(size_t)h * 2048 + n0n + tid];
        }
        #pragma unroll
        for (int rt = 0; rt < 4; ++rt) {
            shortx8 qa0 = *(const shortx8*)(qb + SWZ(rt * 16 + ln, quad * 16));
            shortx8 qa1 = *(const shortx8*)(qb + SWZ(rt * 16 + ln, 64 + quad * 16));
            floatx4 acc = {};
            acc = __builtin_amdgcn_mfma_f32_16x16x32_bf16(qa0, kf[0], acc, 0, 0, 0);
            acc = __builtin_amdgcn_mfma_f32_16x16x32_bf16(qa1, kf[1], acc, 0, 0, 0);
            #pragma unroll
            for (int r = 0; r < 4; ++r)
                gacc += __builtin_amdgcn_exp2f(acc[r]) * us[rt * 16 + quad * 4 + r];
        }
        __syncthreads();
        rb = wb;
    }

    // ---- column totals g_s, then fold r_part = g . values ------------------
    gacc += __shfl_xor(gacc, 16);
    gacc += __shfl_xor(gacc, 32);
    if (quad == 0) g_s[w * 16 + ln] = gacc;   // column m = mb + w*16 + ln
    __syncthreads();
    {
        int grp = tid >> 6, v = tid & 63;
        float acc = 0.f;
        #pragma unroll
        for (int j = 0; j < 16; ++j)
            acc += g_s[grp * 16 + j] *
                   values[(size_t)(mb + grp * 16 + j) * 64 + v];
        Rred[grp * 64 + v] = acc;
    }
    __syncthreads();
    if (tid < 64)
        atomicAdd(&r_ws[h * 64 + tid],
                  Rred[tid] + Rred[64 + tid] + Rred[128 + tid] + Rred[192 + tid]);
}

// =================== pool: pooled[d] = 2048*sum_h bv + sum_hv r*Wv ----------
__global__ __launch_bounds__(256) void pool_kernel(
    const float* __restrict__ Wv, const float* __restrict__ bv,
    const float* __restrict__ r_ws, float* __restrict__ pooled) {
    const int tid = threadIdx.x;
    const int d0 = blockIdx.x * 16;       // grid 64
    const int d = tid & 15, hh = tid >> 4;
    __shared__ float red[16][17];
    float acc = bv[hh * 1024 + d0 + d] * 2048.0f;
    const float* rv = r_ws + hh * 64;
    const float* wp = Wv + (size_t)hh * 64 * 1024 + d0 + d;
    #pragma unroll 8
    for (int v = 0; v < 64; ++v) acc += rv[v] * wp[(size_t)v * 1024];
    red[hh][d] = acc;
    __syncthreads();
    if (tid < 16) {
        float s = 0.f;
        #pragma unroll
        for (int g = 0; g < 16; ++g) s += red[g][tid];
        pooled[d0 + tid] = s;
    }
}

// =================== out: out[dp] = pooled . Wo[dp,:] + bo[dp] ---------------
__global__ __launch_bounds__(256) void out_kernel(
    const float* __restrict__ Wo, const float* __restrict__ bo,
    const float* __restrict__ pooled, float* __restrict__ out) {
    const int tid = threadIdx.x, w = tid >> 6, lane = tid & 63;
    const int dp = blockIdx.x * 4 + w;    // grid 256
    const float* wr = Wo + (size_t)dp * 1024 + lane * 16;
    const float* pp = pooled + lane * 16;
    float acc = 0.f;
    #pragma unroll
    for (int u = 0; u < 4; ++u) {
        float4 a = *(const float4*)&wr[u * 4];
        float4 p = *(const float4*)&pp[u * 4];
        acc += a.x * p.x + a.y * p.y + a.z * p.z + a.w * p.w;
    }
    #pragma unroll
    for (int o = 32; o > 0; o >>= 1) acc += __shfl_xor(acc, o);
    if (lane == 0) out[dp] = acc + bo[dp];
}

extern "C" void kernel_launch(void* const* d_in, const int* in_sizes, int n_in,
                              void* d_out, int out_size, void* d_ws, size_t ws_size,
                              hipStream_t stream) {
    const float* queries = (const float*)d_in[0];
    const float* keys    = (const float*)d_in[1];
    const float* values  = (const float*)d_in[2];
    const float* Wq      = (const float*)d_in[3];
    const float* bq      = (const float*)d_in[4];
    const float* Wk      = (const float*)d_in[5];
    // d_in[6] = bk: row-constant under softmax, unused
    const float* Wv      = (const float*)d_in[7];
    const float* bv      = (const float*)d_in[8];
    const float* Wo      = (const float*)d_in[9];
    const float* bo      = (const float*)d_in[10];
    float* out = (float*)d_out;

    // workspace layout (bytes). Qhs (4MB) overlays Apart+vhpart: Apart/vhpart
    // are dead after reduceA, and pass1 (which writes Qhs) launches after it.
    char* base = (char*)d_ws;
    unsigned short* Qhs = (unsigned short*)base;             // 16*2048*64 bf16 = 4MB
    float* Apart  = (float*)base;                            // 128*4096 f (overlay)
    float* vhpart = Apart + 524288;                          // 128*64 f (overlay)
    float* u_ws   = (float*)(base + 4194304);                // 16*2048 f
    float* r_ws   = (float*)(base + 4325376);                // 1024 f
    float* pooled = (float*)(base + 4329472);                // 1024 f
    unsigned short* Kb   = (unsigned short*)(base + 4333568);  // 2048*64 bf16
    unsigned short* Atlg = (unsigned short*)(base + 4595712);  // 16*64*64 bf16
    float* vhg    = (float*)(base + 4726784);                // 16*64 f
    // total ws: ~4.52 MB

    prep_kernel<<<144, 256, 0, stream>>>(Wq, Wk, bq, keys,
                                         Apart, vhpart, Kb, r_ws);
    reduceA_kernel<<<64, 256, 0, stream>>>(Apart, vhpart, Atlg, vhg);
    pass1_kernel<<<dim3(32, 16), 256, 0, stream>>>(queries, Atlg, vhg,
                                                   Kb, Qhs, u_ws);
    pass2_kernel<<<dim3(32, 16), 256, 0, stream>>>(Qhs, u_ws, Kb, values, r_ws);
    pool_kernel<<<64, 256, 0, stream>>>(Wv, bv, r_ws, pooled);
    out_kernel<<<256, 256, 0, stream>>>(Wo, bo, pooled, out);
}